// Round 9
// baseline (50.578 us; speedup 1.0000x reference)
//
#include <hip/hip_runtime.h>

#define TPB     256
#define LSEQ    1024          // L
#define NCOL    1022          // n = L-2 (columns)
#define NROW    1021          // cumprod rows
#define NPAD    1024          // leading zeros -> no index clamp, aligned b128 reads
#define SLDS    2048          // NPAD + NCOL + tail pad
#define NCHUNK  8
#define RPC     128           // rows per chunk (last: 125)
#define WS_STRIDE 1024        // floats per (c,bd) row in ws
#define WS_NEED  ((NCHUNK - 1) * 64 * WS_STRIDE * sizeof(float))  // 1.75 MB

typedef float v2f __attribute__((ext_vector_type(2)));
typedef float v4f __attribute__((ext_vector_type(4)));

__device__ __forceinline__ float clamp01(float x) {
    return fminf(fmaxf(x, 0.0f), 1.0f);          // v_med3_f32
}

// Shared staging: direction-applied s into zero-padded LDS.
__device__ __forceinline__ void stage(float* sp, const float* score,
                                      const int* score_idx, int b, int d, int tid) {
    for (int i = tid; i < NPAD; i += TPB) sp[i] = 0.0f;
    if (tid < 2) sp[NPAD + NCOL + tid] = 0.0f;
    const int* idxRow = score_idx + b * LSEQ + 1;       // docs[b][1:]
    for (int i = tid; i < NCOL; i += TPB) {
        int src = d ? (NCOL - 1 - i) : i;
        sp[NPAD + i] = score[idxRow[src]];
    }
    __syncthreads();
}

// p(r,j) = clamp01((v - s[j])*10 + 1), v = s[j-1-r] (0 via LDS zero-pad).
#define STEP(X)                                                     \
    {   float _x = (X);                                             \
        float p0 = clamp01(__builtin_fmaf(_x, 10.0f, c0));          \
        float p1 = clamp01(__builtin_fmaf(C1, 10.0f, c1));          \
        float p2 = clamp01(__builtin_fmaf(C2, 10.0f, c2));          \
        float p3 = clamp01(__builtin_fmaf(C3, 10.0f, c3));          \
        a0 *= p0; a1 *= p1; a2 *= p2; a3 *= p3;                     \
        C3 = C2; C2 = C1; C1 = _x; }

// ---- Kernel 1: local chunk products P_c(j) over rows [128c,128c+128) ----
// grid = (NCHUNK-1)*64; chunk 7's product is never consumed.
__global__ __launch_bounds__(TPB) void gate_partial(
    const float* __restrict__ score,
    const int*   __restrict__ score_idx,
    float*       __restrict__ ws)
{
    __shared__ __align__(16) float sp[SLDS];
    const int bid = blockIdx.x;
    const int c   = bid >> 6;            // 0..6
    const int bd  = bid & 63;
    stage(sp, score, score_idx, bd >> 1, bd & 1, threadIdx.x);

    const int j  = threadIdx.x * 4;
    const int r0 = c * RPC;
    const float c0 = 1.0f - 10.0f * sp[NPAD + j    ];
    const float c1 = 1.0f - 10.0f * sp[NPAD + j + 1];
    const float c2 = 1.0f - 10.0f * sp[NPAD + j + 2];
    const float c3 = 1.0f - 10.0f * sp[NPAD + j + 3];

    float a0 = 1.0f, a1 = 1.0f, a2 = 1.0f, a3 = 1.0f;
    float C1 = sp[NPAD + j - r0], C2 = sp[NPAD + j + 1 - r0], C3 = sp[NPAD + j + 2 - r0];
    int   m  = NPAD + j - 1 - r0;

    #pragma unroll 1
    for (int bt = 0; bt < RPC / 8; ++bt) {
        v4f hi = *(const v4f*)&sp[m - 3];
        v4f lo = *(const v4f*)&sp[m - 7];
        m -= 8;
        STEP(hi.w); STEP(hi.z); STEP(hi.y); STEP(hi.x);
        STEP(lo.w); STEP(lo.z); STEP(lo.y); STEP(lo.x);
    }
    v4f P; P.x = a0; P.y = a1; P.z = a2; P.w = a3;
    *(v4f*)&ws[(size_t)bid * WS_STRIDE + j] = P;
}

// ---- Kernel 2: entry product from ws, then pure 128-row store loop ----
template <bool USE_WS>
__global__ __launch_bounds__(TPB) void gate_store(
    const float* __restrict__ score,
    const int*   __restrict__ score_idx,
    const float* __restrict__ ws,
    float*       __restrict__ out)
{
    __shared__ __align__(16) float sp[SLDS];
    const int bid = blockIdx.x;
    const int ch  = bid >> 6;            // 0..7
    const int bd  = bid & 63;            // XCD = bd % 8
    stage(sp, score, score_idx, bd >> 1, bd & 1, threadIdx.x);

    const int tid = threadIdx.x;
    const int j   = tid * 4;
    const int r0  = ch * RPC;
    const float c0 = 1.0f - 10.0f * sp[NPAD + j    ];
    const float c1 = 1.0f - 10.0f * sp[NPAD + j + 1];
    const float c2 = 1.0f - 10.0f * sp[NPAD + j + 2];
    const float c3 = 1.0f - 10.0f * sp[NPAD + j + 3];

    float a0 = 1.0f, a1 = 1.0f, a2 = 1.0f, a3 = 1.0f;
    float C1, C2, C3;
    int   m;

    if (USE_WS) {
        // entry accumulator = product of preceding chunks' local products
        for (int c = 0; c < ch; ++c) {
            v4f P = *(const v4f*)&ws[(size_t)(c * 64 + bd) * WS_STRIDE + j];
            a0 *= P.x; a1 *= P.y; a2 *= P.z; a3 *= P.w;
        }
        C1 = sp[NPAD + j - r0]; C2 = sp[NPAD + j + 1 - r0]; C3 = sp[NPAD + j + 2 - r0];
        m  = NPAD + j - 1 - r0;
    } else {
        // fallback: serial prefix walk (R8 behavior)
        C1 = sp[NPAD + j]; C2 = sp[NPAD + j + 1]; C3 = sp[NPAD + j + 2];
        m  = NPAD + j - 1;
        #pragma unroll 1
        for (int bt = 0; bt < (r0 >> 3); ++bt) {
            v4f hi = *(const v4f*)&sp[m - 3];
            v4f lo = *(const v4f*)&sp[m - 7];
            m -= 8;
            STEP(hi.w); STEP(hi.z); STEP(hi.y); STEP(hi.x);
            STEP(lo.w); STEP(lo.z); STEP(lo.y); STEP(lo.x);
        }
    }

    const int nrows = (r0 + RPC < NROW) ? RPC : (NROW - r0);   // 128 or 125
    const bool half = (tid == TPB - 1);
    float* outp = out + (size_t)bd * NROW * NCOL + (size_t)r0 * NCOL + j;

#define EMIT                                                        \
    {   if (half) { v2f w2; w2.x = a0; w2.y = a1; *(v2f*)outp = w2; } \
        else      { v4f w; w.x = a0; w.y = a1; w.z = a2; w.w = a3;  \
                    *(v4f*)outp = w; }                              \
        outp += NCOL; }

    #pragma unroll 1
    for (int bt = 0; bt < nrows / 8; ++bt) {
        v4f hi = *(const v4f*)&sp[m - 3];
        v4f lo = *(const v4f*)&sp[m - 7];
        m -= 8;
        STEP(hi.w); EMIT; STEP(hi.z); EMIT; STEP(hi.y); EMIT; STEP(hi.x); EMIT;
        STEP(lo.w); EMIT; STEP(lo.z); EMIT; STEP(lo.y); EMIT; STEP(lo.x); EMIT;
    }
    #pragma unroll 1
    for (int r = nrows & ~7; r < nrows; ++r) {    // tail: 5 rows, last chunk
        float x = sp[m]; --m;
        STEP(x); EMIT;
    }
#undef EMIT
}

extern "C" void kernel_launch(void* const* d_in, const int* in_sizes, int n_in,
                              void* d_out, int out_size, void* d_ws, size_t ws_size,
                              hipStream_t stream)
{
    const float* score = (const float*)d_in[0];
    const int*   sidx  = (const int*)d_in[1];
    float*       out   = (float*)d_out;
    float*       ws    = (float*)d_ws;

    if (ws_size >= WS_NEED) {
        gate_partial<<<dim3((NCHUNK - 1) * 64), dim3(TPB), 0, stream>>>(score, sidx, ws);
        gate_store<true><<<dim3(NCHUNK * 64), dim3(TPB), 0, stream>>>(score, sidx, ws, out);
    } else {
        gate_store<false><<<dim3(NCHUNK * 64), dim3(TPB), 0, stream>>>(score, sidx, ws, out);
    }
}

// Round 10
// 44.457 us; speedup vs baseline: 1.1377x; 1.1377x over previous
//
#include <hip/hip_runtime.h>

#define TPB     256
#define LSEQ    1024          // L
#define NCOL    1022          // n = L-2 (columns)
#define NROW    1021          // cumprod rows
#define NPAD    1024          // leading zeros -> no index clamp, aligned b128 reads
#define SLDS    2048          // NPAD + NCOL + tail pad
#define NCHUNK  8
#define RPC     128           // rows per chunk (last: 125)

typedef float v2f __attribute__((ext_vector_type(2)));
typedef float v4f __attribute__((ext_vector_type(4)));

__device__ __forceinline__ float clamp01(float x) {
    return fminf(fmaxf(x, 0.0f), 1.0f);          // v_med3_f32
}

// R8 structure (single-owner full-row blocks, 4 cols/thread, float4 stores)
// with NCHUNK=8 / RPC=128 -> 512 blocks = 2 blocks/CU. One block's serial
// store-free prefix VALU overlaps the co-resident block's saturated stores,
// removing R8's ~7.6us prefix stagger. Round-robin dispatch pairs (bd,ch)
// with (bd,ch+4) per CU: one short prefix + one long. Chunk regions stay
// contiguous and 128B-aligned (128*4088 % 128 == 0) -> no cross-block split
// lines. bid = ch*64 + bd keeps XCD = bd%8 (all chunks of a matrix on one XCD).
__global__ __launch_bounds__(TPB) void gate_kernel(
    const float* __restrict__ score,
    const int*   __restrict__ score_idx,
    float*       __restrict__ out)
{
    __shared__ __align__(16) float sp[SLDS];

    const int bid = blockIdx.x;
    const int ch  = bid >> 6;            // chunk 0..7
    const int bd  = bid & 63;            // b*2 + d   (XCD = bd % 8)
    const int d   = bd & 1;
    const int b   = bd >> 1;
    const int tid = threadIdx.x;

    for (int i = tid; i < NPAD; i += TPB) sp[i] = 0.0f;
    if (tid < 2) sp[NPAD + NCOL + tid] = 0.0f;          // tail pad
    const int* idxRow = score_idx + b * LSEQ + 1;       // docs[b][1:]
    for (int i = tid; i < NCOL; i += TPB) {
        int src = d ? (NCOL - 1 - i) : i;
        sp[NPAD + i] = score[idxRow[src]];
    }
    __syncthreads();

    const int j = tid * 4;               // columns j..j+3 (t=255: j+2,j+3 pad)
    const float c0 = 1.0f - 10.0f * sp[NPAD + j    ];
    const float c1 = 1.0f - 10.0f * sp[NPAD + j + 1];
    const float c2 = 1.0f - 10.0f * sp[NPAD + j + 2];
    const float c3 = 1.0f - 10.0f * sp[NPAD + j + 3];

    float a0 = 1.0f, a1 = 1.0f, a2 = 1.0f, a3 = 1.0f;
    float C1 = sp[NPAD + j], C2 = sp[NPAD + j + 1], C3 = sp[NPAD + j + 2];
    int   m  = NPAD + j - 1;             // fresh-value index (col j), descending

#define STEP(X)                                                     \
    {   float _x = (X);                                             \
        float p0 = clamp01(__builtin_fmaf(_x, 10.0f, c0));          \
        float p1 = clamp01(__builtin_fmaf(C1, 10.0f, c1));          \
        float p2 = clamp01(__builtin_fmaf(C2, 10.0f, c2));          \
        float p3 = clamp01(__builtin_fmaf(C3, 10.0f, c3));          \
        a0 *= p0; a1 *= p1; a2 *= p2; a3 *= p3;                     \
        C3 = C2; C2 = C1; C1 = _x; }

    // ---------- prefix: rows [0, 128*ch), no stores ----------
    #pragma unroll 1
    for (int bt = 0; bt < ch * (RPC / 8); ++bt) {
        v4f hi = *(const v4f*)&sp[m - 3];    // 16B-aligned (NPAD=1024)
        v4f lo = *(const v4f*)&sp[m - 7];
        m -= 8;
        STEP(hi.w); STEP(hi.z); STEP(hi.y); STEP(hi.x);
        STEP(lo.w); STEP(lo.z); STEP(lo.y); STEP(lo.x);
    }

    // ---------- store loop: rows [r0, r1) ----------
    const int r0 = ch * RPC;
    const int nrows = (r0 + RPC < NROW) ? RPC : (NROW - r0);   // 128 or 125
    const bool half = (tid == TPB - 1);  // last thread: only 2 real columns

    float* outp = out + (size_t)bd * NROW * NCOL + (size_t)r0 * NCOL + j;

#define EMIT                                                        \
    {   if (half) { v2f w2; w2.x = a0; w2.y = a1; *(v2f*)outp = w2; } \
        else      { v4f w; w.x = a0; w.y = a1; w.z = a2; w.w = a3;  \
                    *(v4f*)outp = w; }                              \
        outp += NCOL; }

    #pragma unroll 1
    for (int bt = 0; bt < nrows / 8; ++bt) {
        v4f hi = *(const v4f*)&sp[m - 3];
        v4f lo = *(const v4f*)&sp[m - 7];
        m -= 8;
        STEP(hi.w); EMIT; STEP(hi.z); EMIT; STEP(hi.y); EMIT; STEP(hi.x); EMIT;
        STEP(lo.w); EMIT; STEP(lo.z); EMIT; STEP(lo.y); EMIT; STEP(lo.x); EMIT;
    }
    #pragma unroll 1
    for (int r = nrows & ~7; r < nrows; ++r) {    // tail: 5 rows, last chunk
        float x = sp[m]; --m;
        STEP(x); EMIT;
    }
#undef STEP
#undef EMIT
}

extern "C" void kernel_launch(void* const* d_in, const int* in_sizes, int n_in,
                              void* d_out, int out_size, void* d_ws, size_t ws_size,
                              hipStream_t stream)
{
    const float* score = (const float*)d_in[0];
    const int*   sidx  = (const int*)d_in[1];
    float*       out   = (float*)d_out;

    const int B = in_sizes[0] / LSEQ;    // 32
    dim3 grid(B * 2 * NCHUNK), block(TPB);   // 512 blocks x 256 threads
    gate_kernel<<<grid, block, 0, stream>>>(score, sidx, out);
}